// Round 13
// baseline (44.175 us; speedup 1.0000x reference)
//
#include <hip/hip_runtime.h>

// VQ-VAE codebook: z [32,64,32,32] f32 NCHW, embedding [1024,64] f32.
// Outputs (concat, f32): z_q NCHW (2097152) | indices as float (32768) | loss (1).
//
// R13: R12's screen fed MFMA well but every wave read ALL 64 groups from LDS
// (4x redundancy, ~10 us LDS floor). Now wave = (row-half, k-half): each wave
// reads its 4 groups/tile, shared across 2 row-tiles -> block LDS reads halve
// twice (1 MB -> 512 KB). Candidates: per-k-half screen top-2 (4/row) written
// race-free to g_top[n][kh*2+..]; vq_fin exact-fp32-verifies all 4 (superset
// of global screen top-2; ties -> smallest k via u64 keys).

#define IDX_OFF 2097152
#define LOSS_OFF 2129920
#define BIGF 512.0f
#define RL 72
#define U64INF 0xFFFFFFFFFFFFFFFFull

typedef __attribute__((ext_vector_type(8))) short bf16x8;
typedef __attribute__((ext_vector_type(4))) float f32x4;

__device__ __align__(256) float g_ep[1024 * RL];     // [-2e | ||e||^2+512 | pad]
__device__ __align__(256) float g_enb[1024];         // dense ||e||^2+512
__device__ __align__(256) unsigned short g_bf[64 * 4 * 64 * 8]; // [g][f][lane][j]
__device__ unsigned long long g_top[32768][4];       // 4 screen candidates/row
__device__ float g_partial[512];

typedef const __attribute__((address_space(1))) void* gvp;
typedef __attribute__((address_space(3))) void* lvp;

__device__ __forceinline__ void gll16(const void* g, void* l) {
    __builtin_amdgcn_global_load_lds((gvp)g, (lvp)l, 16, 0, 0);
}

__device__ __forceinline__ unsigned int f2bf(float f) {   // fp32 -> bf16, RTN-even
    unsigned int u = __float_as_uint(f);
    return (u + 0x7FFFu + ((u >> 16) & 1u)) >> 16;
}

__device__ __forceinline__ unsigned long long min16(unsigned long long x) {
#pragma unroll
    for (int o = 1; o < 16; o <<= 1) {
        unsigned long long y = __shfl_xor(x, o, 64);
        x = y < x ? y : x;
    }
    return x;
}

// ---------------- kernel 0: build e', enb, packed B-frags ------------------
// B-frag layout (R11/R12-verified): group g, lane l (col=l&15, g4=l>>4):
// f=0: bf16(-2e)[g*16+col][g4*8+j]   f=1: ...[32+g4*8+j]
// f=2: lo-residual, same indexing    f=3: ...
// at g_bf[((g*4+f)*64 + l)*8 + j] -> linear staging + conflict-free ds_read.
__global__ __launch_bounds__(256) void vq_prep(const float* __restrict__ e) {
    int lane = threadIdx.x & 63;
    int k    = blockIdx.x * 4 + (threadIdx.x >> 6);
    float v  = e[k * 64 + lane];
    float m2 = -2.0f * v;
    float s  = v * v;
#pragma unroll
    for (int o = 32; o; o >>= 1) s += __shfl_xor(s, o, 64);
    g_ep[(size_t)k * RL + lane] = m2;
    if (lane == 0) { g_ep[(size_t)k * RL + 64] = s + BIGF; g_enb[k] = s + BIGF; }
    unsigned hb = f2bf(m2);
    float    hf = __uint_as_float(hb << 16);
    unsigned lb = f2bf(m2 - hf);
    int g  = k >> 4, c = k & 15;
    int ch = lane >> 5, dc = lane & 31;
    int g4 = dc >> 3,  j = dc & 7;
    int l  = g4 * 16 + c;
    g_bf[(size_t)((g * 4 + ch) * 64 + l) * 8 + j]     = (unsigned short)hb;
    g_bf[(size_t)((g * 4 + 2 + ch) * 64 + l) * 8 + j] = (unsigned short)lb;
}

// ---------------- kernel 1: MFMA screen ------------------------------------
// grid 512: 64 rows/block, 4 waves. Wave w: row-half rh=w&1 (row-tiles
// 2rh, 2rh+1), k-half kh=w>>1 (groups g with ((g>>2)&1)==kh; within tile tt
// of 8 groups, local gg = kh*4+i). B-frag reads shared across 2 row-tiles.
__global__ __launch_bounds__(256, 2) void vq_main(const float* __restrict__ z) {
    __shared__ float enb[1024];
    __shared__ unsigned short bf[2][8 * 2048];   // 2 x 32 KB

    const int t    = threadIdx.x;
    const int lane = t & 63;
    const int w    = __builtin_amdgcn_readfirstlane(t >> 6);  // 0..3
    const int col  = lane & 15;
    const int g4   = lane >> 4;
    const int rh   = w & 1;
    const int kh   = w >> 1;
    const int bid  = blockIdx.x;      // 0..511
    const int b    = bid >> 4;
    const int hw0  = (bid & 15) << 6;

    // stage enb (4 KB) + B-tile 0 (32 KB) via linear DMA
    gll16((const char*)g_enb + w * 1024 + lane * 16, (char*)enb + w * 1024);
#pragma unroll
    for (int i = 0; i < 8; ++i) {
        int seg = w * 8 + i;
        gll16((const char*)g_bf + seg * 1024 + lane * 16, (char*)&bf[0][0] + seg * 1024);
    }

    // A-fragments for both of this wave's row-tiles (computed -> VGPR-resident)
    bf16x8 zh[2][2], zl[2][2];
#pragma unroll
    for (int rt = 0; rt < 2; ++rt) {
        const float* zr = z + (size_t)b * 65536 + hw0 + ((2 * rh + rt) * 16 + col);
#pragma unroll
        for (int c = 0; c < 2; ++c)
#pragma unroll
            for (int j = 0; j < 8; ++j) {
                int d = c * 32 + g4 * 8 + j;
                float f = zr[(size_t)d * 1024];
                unsigned hb = f2bf(f);
                float    hf = __uint_as_float(hb << 16);
                unsigned lb = f2bf(f - hf);
                zh[rt][c][j] = (short)hb;
                zl[rt][c][j] = (short)lb;
            }
    }

    unsigned long long t0[2][4], t1[2][4];
#pragma unroll
    for (int rt = 0; rt < 2; ++rt)
#pragma unroll
        for (int r = 0; r < 4; ++r) { t0[rt][r] = U64INF; t1[rt][r] = U64INF; }

    __syncthreads();   // DMA drained -> tile 0 + enb visible

    for (int tt = 0; tt < 8; ++tt) {
        const int cur = tt & 1;
        if (tt < 7) {   // prefetch next tile (fire-and-forget DMA)
#pragma unroll
            for (int i = 0; i < 8; ++i) {
                int seg = w * 8 + i;
                gll16((const char*)g_bf + (tt + 1) * 32768 + seg * 1024 + lane * 16,
                      (char*)&bf[cur ^ 1][0] + seg * 1024);
            }
        }

        const unsigned short* bfc = &bf[cur][0];
#pragma unroll
        for (int i = 0; i < 4; ++i) {
            const int gg = kh * 4 + i;            // this wave's groups in tile
            const int kc = (tt * 8 + gg) * 16 + col;
            const bf16x8* p = (const bf16x8*)(bfc + gg * 2048);
            bf16x8 eh0 = p[0 * 64 + lane];        // contiguous ds_read_b128
            bf16x8 eh1 = p[1 * 64 + lane];
            bf16x8 el0 = p[2 * 64 + lane];
            bf16x8 el1 = p[3 * 64 + lane];
            float enbv = enb[kc];

#pragma unroll
            for (int rt = 0; rt < 2; ++rt) {
                f32x4 acc = {0.f, 0.f, 0.f, 0.f};
                acc = __builtin_amdgcn_mfma_f32_16x16x32_bf16(zh[rt][0], eh0, acc, 0, 0, 0);
                acc = __builtin_amdgcn_mfma_f32_16x16x32_bf16(zh[rt][1], eh1, acc, 0, 0, 0);
                acc = __builtin_amdgcn_mfma_f32_16x16x32_bf16(zh[rt][0], el0, acc, 0, 0, 0);
                acc = __builtin_amdgcn_mfma_f32_16x16x32_bf16(zh[rt][1], el1, acc, 0, 0, 0);
                acc = __builtin_amdgcn_mfma_f32_16x16x32_bf16(zl[rt][0], eh0, acc, 0, 0, 0);
                acc = __builtin_amdgcn_mfma_f32_16x16x32_bf16(zl[rt][1], eh1, acc, 0, 0, 0);
#pragma unroll
                for (int r = 0; r < 4; ++r) {
                    float cand = acc[r] + enbv;   // >0 (bias) -> uint order = float order
                    unsigned long long key =
                        ((unsigned long long)__float_as_uint(cand) << 32) | (unsigned)kc;
                    unsigned long long nt1 = key < t0[rt][r] ? t0[rt][r]
                                           : (key < t1[rt][r] ? key : t1[rt][r]);
                    unsigned long long nt0 = key < t0[rt][r] ? key : t0[rt][r];
                    t0[rt][r] = nt0; t1[rt][r] = nt1;
                }
            }
        }
        __syncthreads();   // readers done with bf[cur]; next DMA drained
    }

    // per row: this k-half's top-2 over cols (min16 within 16-lane group)
#pragma unroll
    for (int rt = 0; rt < 2; ++rt)
#pragma unroll
        for (int r = 0; r < 4; ++r) {
            unsigned long long a = t0[rt][r];
            unsigned long long m1 = min16(a);
            if (a == m1) a = t1[rt][r];     // keys unique: exactly one lane swaps
            unsigned long long m2 = min16(a);
            int n = bid * 64 + (2 * rh + rt) * 16 + g4 * 4 + r;
            if (col == 0) g_top[n][kh * 2 + 0] = m1;
            if (col == 1) g_top[n][kh * 2 + 1] = m2;
        }
}

// ---------------- kernel 2: exact re-verify (4 cands) + z_q + idx + loss ---
__global__ __launch_bounds__(256) void vq_fin(const float* __restrict__ z,
                                              const float* __restrict__ e,
                                              float* __restrict__ out) {
    __shared__ float sred[4][64][4];
    __shared__ int   ishare[64];
    __shared__ float lred[4];
    int lane = threadIdx.x & 63;
    int w    = threadIdx.x >> 6;
    int rg   = blockIdx.x;          // 0..511 rowgroups of 64
    int n    = rg * 64 + lane;
    int b    = rg >> 4;
    int hw0  = (rg & 15) << 6;

    int kc[4];
#pragma unroll
    for (int c = 0; c < 4; ++c) kc[c] = (int)(g_top[n][c] & 0xFFFFFFFFull);

    const float* zbase = z + (size_t)b * 65536 + hw0 + lane;
    float p[4] = {0.f, 0.f, 0.f, 0.f};
#pragma unroll
    for (int j = 0; j < 16; ++j) {
        int d = w * 16 + j;
        float zv = zbase[(size_t)d * 1024];
#pragma unroll
        for (int c = 0; c < 4; ++c)
            p[c] = fmaf(zv, g_ep[(size_t)kc[c] * RL + d], p[c]);
    }
#pragma unroll
    for (int c = 0; c < 4; ++c) sred[w][lane][c] = p[c];
    __syncthreads();

    if (w == 0) {
        unsigned long long ky = U64INF;
#pragma unroll
        for (int c = 0; c < 4; ++c) {
            float dc = sred[0][lane][c] + sred[1][lane][c]
                     + sred[2][lane][c] + sred[3][lane][c]
                     + g_ep[(size_t)kc[c] * RL + 64];
            unsigned long long kx =
                ((unsigned long long)__float_as_uint(dc) << 32) | (unsigned)kc[c];
            ky = kx < ky ? kx : ky;      // exact fp32 min; ties -> smallest k
        }
        int idx = (int)(ky & 0xFFFFFFFFull);
        out[IDX_OFF + n] = (float)idx;
        ishare[lane] = idx;
    }
    __syncthreads();

    int idx = ishare[lane];
    float*        qbase = out + (size_t)b * 65536 + hw0 + lane;
    const float4* er4   = (const float4*)(e + (size_t)idx * 64) + (w << 2);

    float lsum = 0.f;
#pragma unroll
    for (int pq = 0; pq < 4; ++pq) {
        float4 ev = er4[pq];                       // gather, L2-resident
        int d = (w << 4) + (pq << 2);
        float ezw[4] = {ev.x, ev.y, ev.z, ev.w};
#pragma unroll
        for (int qq = 0; qq < 4; ++qq) {
            float zv = zbase[(size_t)(d + qq) * 1024];
            float df = ezw[qq] - zv;
            lsum = fmaf(df, df, lsum);
            qbase[(size_t)(d + qq) * 1024] = ezw[qq]; // coalesced along hw
        }
    }
#pragma unroll
    for (int o = 32; o; o >>= 1) lsum += __shfl_xor(lsum, o, 64);
    if (lane == 0) lred[w] = lsum;
    __syncthreads();
    if (threadIdx.x == 0)
        g_partial[rg] = (lred[0] + lred[1]) + (lred[2] + lred[3]);
}

// ---------------- kernel 3: loss scalar ------------------------------------
__global__ __launch_bounds__(64) void vq_finish(float* __restrict__ out) {
    int lane = threadIdx.x;
    float s = 0.f;
#pragma unroll
    for (int i = 0; i < 8; ++i) s += g_partial[lane * 8 + i];
#pragma unroll
    for (int o = 32; o; o >>= 1) s += __shfl_xor(s, o, 64);
    // loss = q_latent + 0.25*e_latent = 1.25 * mean((z_q - z)^2)
    if (lane == 0) out[LOSS_OFF] = s * (1.25f / 2097152.0f);
}

extern "C" void kernel_launch(void* const* d_in, const int* in_sizes, int n_in,
                              void* d_out, int out_size, void* d_ws, size_t ws_size,
                              hipStream_t stream) {
    const float* z = (const float*)d_in[0];
    const float* e = (const float*)d_in[1];
    float* out = (float*)d_out;

    vq_prep<<<256, 256, 0, stream>>>(e);
    vq_main<<<512, 256, 0, stream>>>(z);
    vq_fin<<<512, 256, 0, stream>>>(z, e, out);
    vq_finish<<<1, 64, 0, stream>>>(out);
}

// Round 14
// 40.561 us; speedup vs baseline: 1.0891x; 1.0891x over previous
//
#include <hip/hip_runtime.h>

// VQ-VAE codebook: z [32,64,32,32] f32 NCHW, embedding [1024,64] f32.
// Outputs (concat, f32): z_q NCHW (2097152) | indices as float (32768) | loss (1).
//
// R14: fuse verify+epilogue into the screen kernel. R12/R13 showed the screen
// is fed fine; the remaining cost was structural: vq_fin's launch + cold z
// re-read + g_top global round-trip. A block covers 64 rows x all 1024 codes,
// so candidates are block-local: screen top-2 per (row, k-half) -> LDS ->
// 4 waves exact-fp32-verify the 4 slots -> idx/z_q/loss in-kernel. Tiles
// shrink to 4 groups (dbuf 32 KB, ~41 KB LDS) -> 3 blocks/CU.

#define IDX_OFF 2097152
#define LOSS_OFF 2129920
#define BIGF 512.0f
#define RL 72
#define U64INF 0xFFFFFFFFFFFFFFFFull

typedef __attribute__((ext_vector_type(8))) short bf16x8;
typedef __attribute__((ext_vector_type(4))) float f32x4;

__device__ __align__(256) float g_ep[1024 * RL];     // [-2e | ||e||^2+512 | pad]
__device__ __align__(256) float g_enb[1024];         // dense ||e||^2+512
__device__ __align__(256) unsigned short g_bf[64 * 4 * 64 * 8]; // [g][f][lane][j]
__device__ float g_partial[512];

typedef const __attribute__((address_space(1))) void* gvp;
typedef __attribute__((address_space(3))) void* lvp;

__device__ __forceinline__ void gll16(const void* g, void* l) {
    __builtin_amdgcn_global_load_lds((gvp)g, (lvp)l, 16, 0, 0);
}

__device__ __forceinline__ unsigned int f2bf(float f) {   // fp32 -> bf16, RTN-even
    unsigned int u = __float_as_uint(f);
    return (u + 0x7FFFu + ((u >> 16) & 1u)) >> 16;
}

__device__ __forceinline__ unsigned long long min16(unsigned long long x) {
#pragma unroll
    for (int o = 1; o < 16; o <<= 1) {
        unsigned long long y = __shfl_xor(x, o, 64);
        x = y < x ? y : x;
    }
    return x;
}

// ---------------- kernel 0: build e', enb, packed B-frags ------------------
// B-frag layout (R11-verified): group g, lane l (col=l&15, g4=l>>4):
// f=0: bf16(-2e)[g*16+col][g4*8+j]  f=1: ...[32+g4*8+j]  f=2/3: lo-residual.
// g_bf[((g*4+f)*64+l)*8+j] -> linear DMA staging + conflict-free ds_read_b128.
__global__ __launch_bounds__(256) void vq_prep(const float* __restrict__ e) {
    int lane = threadIdx.x & 63;
    int k    = blockIdx.x * 4 + (threadIdx.x >> 6);
    float v  = e[k * 64 + lane];
    float m2 = -2.0f * v;
    float s  = v * v;
#pragma unroll
    for (int o = 32; o; o >>= 1) s += __shfl_xor(s, o, 64);
    g_ep[(size_t)k * RL + lane] = m2;
    if (lane == 0) { g_ep[(size_t)k * RL + 64] = s + BIGF; g_enb[k] = s + BIGF; }
    unsigned hb = f2bf(m2);
    float    hf = __uint_as_float(hb << 16);
    unsigned lb = f2bf(m2 - hf);
    int g  = k >> 4, c = k & 15;
    int ch = lane >> 5, dc = lane & 31;
    int g4 = dc >> 3,  j = dc & 7;
    int l  = g4 * 16 + c;
    g_bf[(size_t)((g * 4 + ch) * 64 + l) * 8 + j]     = (unsigned short)hb;
    g_bf[(size_t)((g * 4 + 2 + ch) * 64 + l) * 8 + j] = (unsigned short)lb;
}

// ---------------- kernel 1: fused screen + verify + epilogue ---------------
// grid 512: 64 rows/block, 4 waves. Screen: wave w = (rh=w&1, kh=w>>1);
// row-tiles 2rh,2rh+1; groups {kh*2, kh*2+1} mod 4 of each 4-group tile.
// Verify: wave w = candidate slot w (2 per k-half), exact fp32, u64-min merge.
__global__ __launch_bounds__(256, 3) void vq_main(const float* __restrict__ z,
                                                  const float* __restrict__ e,
                                                  float* __restrict__ out) {
    __shared__ unsigned short bf[2][4 * 2048];   // 2 x 16 KB
    __shared__ float enb[1024];                  // 4 KB
    __shared__ unsigned long long stop[2][64][2];// top-2 keys per (kh,row) 2 KB
    __shared__ unsigned long long skey[4][64];   // verified keys per slot  2 KB
    __shared__ int   ishare[64];
    __shared__ float lred[4];

    const int t    = threadIdx.x;
    const int lane = t & 63;
    const int w    = __builtin_amdgcn_readfirstlane(t >> 6);  // 0..3
    const int col  = lane & 15;
    const int g4   = lane >> 4;
    const int rh   = w & 1;
    const int kh   = w >> 1;
    const int bid  = blockIdx.x;      // 0..511
    const int b    = bid >> 4;
    const int hw0  = (bid & 15) << 6;

    // stage enb (4 KB) + B-tile 0 (16 KB) via linear DMA
    gll16((const char*)g_enb + w * 1024 + lane * 16, (char*)enb + w * 1024);
#pragma unroll
    for (int i = 0; i < 4; ++i) {
        int seg = w * 4 + i;
        gll16((const char*)g_bf + seg * 1024 + lane * 16, (char*)&bf[0][0] + seg * 1024);
    }

    // A-fragments for both row-tiles (computed -> VGPR-resident)
    bf16x8 zh[2][2], zl[2][2];
#pragma unroll
    for (int rt = 0; rt < 2; ++rt) {
        const float* zr = z + (size_t)b * 65536 + hw0 + ((2 * rh + rt) * 16 + col);
#pragma unroll
        for (int c = 0; c < 2; ++c)
#pragma unroll
            for (int j = 0; j < 8; ++j) {
                int d = c * 32 + g4 * 8 + j;
                float f = zr[(size_t)d * 1024];
                unsigned hb = f2bf(f);
                float    hf = __uint_as_float(hb << 16);
                unsigned lb = f2bf(f - hf);
                zh[rt][c][j] = (short)hb;
                zl[rt][c][j] = (short)lb;
            }
    }

    unsigned long long t0[2][4], t1[2][4];
#pragma unroll
    for (int rt = 0; rt < 2; ++rt)
#pragma unroll
        for (int r = 0; r < 4; ++r) { t0[rt][r] = U64INF; t1[rt][r] = U64INF; }

    __syncthreads();   // DMA drained -> tile 0 + enb visible

    for (int tt = 0; tt < 16; ++tt) {
        const int cur = tt & 1;
        if (tt < 15) {   // prefetch next 16 KB tile (fire-and-forget DMA)
#pragma unroll
            for (int i = 0; i < 4; ++i) {
                int seg = w * 4 + i;
                gll16((const char*)g_bf + (tt + 1) * 16384 + seg * 1024 + lane * 16,
                      (char*)&bf[cur ^ 1][0] + seg * 1024);
            }
        }

        const unsigned short* bfc = &bf[cur][0];
#pragma unroll
        for (int i = 0; i < 2; ++i) {
            const int gg = kh * 2 + i;            // this wave's groups in tile
            const int kc = (tt * 4 + gg) * 16 + col;
            const bf16x8* p = (const bf16x8*)(bfc + gg * 2048);
            bf16x8 eh0 = p[0 * 64 + lane];        // contiguous ds_read_b128
            bf16x8 eh1 = p[1 * 64 + lane];
            bf16x8 el0 = p[2 * 64 + lane];
            bf16x8 el1 = p[3 * 64 + lane];
            float enbv = enb[kc];

#pragma unroll
            for (int rt = 0; rt < 2; ++rt) {
                f32x4 acc = {0.f, 0.f, 0.f, 0.f};
                acc = __builtin_amdgcn_mfma_f32_16x16x32_bf16(zh[rt][0], eh0, acc, 0, 0, 0);
                acc = __builtin_amdgcn_mfma_f32_16x16x32_bf16(zh[rt][1], eh1, acc, 0, 0, 0);
                acc = __builtin_amdgcn_mfma_f32_16x16x32_bf16(zh[rt][0], el0, acc, 0, 0, 0);
                acc = __builtin_amdgcn_mfma_f32_16x16x32_bf16(zh[rt][1], el1, acc, 0, 0, 0);
                acc = __builtin_amdgcn_mfma_f32_16x16x32_bf16(zl[rt][0], eh0, acc, 0, 0, 0);
                acc = __builtin_amdgcn_mfma_f32_16x16x32_bf16(zl[rt][1], eh1, acc, 0, 0, 0);
#pragma unroll
                for (int r = 0; r < 4; ++r) {
                    float cand = acc[r] + enbv;   // >0 (bias) -> uint order = float order
                    unsigned long long key =
                        ((unsigned long long)__float_as_uint(cand) << 32) | (unsigned)kc;
                    unsigned long long nt1 = key < t0[rt][r] ? t0[rt][r]
                                           : (key < t1[rt][r] ? key : t1[rt][r]);
                    unsigned long long nt0 = key < t0[rt][r] ? key : t0[rt][r];
                    t0[rt][r] = nt0; t1[rt][r] = nt1;
                }
            }
        }
        __syncthreads();   // readers done with bf[cur]; next DMA drained
    }

    // per (row, k-half): top-2 over cols -> LDS
#pragma unroll
    for (int rt = 0; rt < 2; ++rt)
#pragma unroll
        for (int r = 0; r < 4; ++r) {
            unsigned long long a = t0[rt][r];
            unsigned long long m1 = min16(a);
            if (a == m1) a = t1[rt][r];     // keys unique: exactly one lane swaps
            unsigned long long m2 = min16(a);
            int rl = (2 * rh + rt) * 16 + g4 * 4 + r;
            if (col == 0) stop[kh][rl][0] = m1;
            if (col == 1) stop[kh][rl][1] = m2;
        }
    __syncthreads();

    // ---- verify: wave w = slot w; lane = row; exact fp32 re-evaluate ----
    {
        unsigned long long ck = (w < 2) ? stop[0][lane][w] : stop[1][lane][w - 2];
        int kc = (int)(ck & 0xFFFFFFFFull);
        const float* zbase = z + (size_t)b * 65536 + hw0 + lane;   // L1/L2-hot
        const float* ep    = g_ep + (size_t)kc * RL;
        float d0 = 0.f, d1 = 0.f, d2 = 0.f, d3 = 0.f;
#pragma unroll
        for (int dq = 0; dq < 16; ++dq) {
            float4 ev = *(const float4*)(ep + dq * 4);
            d0 = fmaf(zbase[(size_t)(dq * 4 + 0) * 1024], ev.x, d0);
            d1 = fmaf(zbase[(size_t)(dq * 4 + 1) * 1024], ev.y, d1);
            d2 = fmaf(zbase[(size_t)(dq * 4 + 2) * 1024], ev.z, d2);
            d3 = fmaf(zbase[(size_t)(dq * 4 + 3) * 1024], ev.w, d3);
        }
        float dist = (d0 + d1) + (d2 + d3) + ep[64];
        skey[w][lane] = ((unsigned long long)__float_as_uint(dist) << 32) | (unsigned)kc;
    }
    __syncthreads();

    if (w == 0) {
        unsigned long long ky = skey[0][lane];
        unsigned long long k1 = skey[1][lane];
        unsigned long long k2 = skey[2][lane];
        unsigned long long k3 = skey[3][lane];
        ky = k1 < ky ? k1 : ky;
        ky = k2 < ky ? k2 : ky;
        ky = k3 < ky ? k3 : ky;         // exact min; ties -> smallest k
        int idx = (int)(ky & 0xFFFFFFFFull);
        out[IDX_OFF + bid * 64 + lane] = (float)idx;
        ishare[lane] = idx;
    }
    __syncthreads();

    // ---- epilogue: z_q (coalesced along hw) + loss partial ----
    {
        int idx = ishare[lane];
        const float*  zbase = z + (size_t)b * 65536 + hw0 + lane;
        float*        qbase = out + (size_t)b * 65536 + hw0 + lane;
        const float4* er4   = (const float4*)(e + (size_t)idx * 64) + (w << 2);

        float lsum = 0.f;
#pragma unroll
        for (int p = 0; p < 4; ++p) {
            float4 ev = er4[p];                        // gather, L2-resident
            int d = (w << 4) + (p << 2);
            float ezw[4] = {ev.x, ev.y, ev.z, ev.w};
#pragma unroll
            for (int qq = 0; qq < 4; ++qq) {
                float zv = zbase[(size_t)(d + qq) * 1024];
                float df = ezw[qq] - zv;
                lsum = fmaf(df, df, lsum);
                qbase[(size_t)(d + qq) * 1024] = ezw[qq];
            }
        }
#pragma unroll
        for (int o = 32; o; o >>= 1) lsum += __shfl_xor(lsum, o, 64);
        if (lane == 0) lred[w] = lsum;
    }
    __syncthreads();
    if (t == 0)
        g_partial[bid] = (lred[0] + lred[1]) + (lred[2] + lred[3]);
}

// ---------------- kernel 2: loss scalar ------------------------------------
__global__ __launch_bounds__(64) void vq_finish(float* __restrict__ out) {
    int lane = threadIdx.x;
    float s = 0.f;
#pragma unroll
    for (int i = 0; i < 8; ++i) s += g_partial[lane * 8 + i];
#pragma unroll
    for (int o = 32; o; o >>= 1) s += __shfl_xor(s, o, 64);
    // loss = q_latent + 0.25*e_latent = 1.25 * mean((z_q - z)^2)
    if (lane == 0) out[LOSS_OFF] = s * (1.25f / 2097152.0f);
}

extern "C" void kernel_launch(void* const* d_in, const int* in_sizes, int n_in,
                              void* d_out, int out_size, void* d_ws, size_t ws_size,
                              hipStream_t stream) {
    const float* z = (const float*)d_in[0];
    const float* e = (const float*)d_in[1];
    float* out = (float*)d_out;

    vq_prep<<<256, 256, 0, stream>>>(e);
    vq_main<<<512, 256, 0, stream>>>(z, e, out);
    vq_finish<<<1, 64, 0, stream>>>(out);
}

// Round 15
// 34.208 us; speedup vs baseline: 1.2913x; 1.1857x over previous
//
#include <hip/hip_runtime.h>

// VQ-VAE codebook: z [32,64,32,32] f32 NCHW, embedding [1024,64] f32.
// Outputs (concat, f32): z_q NCHW (2097152) | indices as float (32768) | loss (1).
//
// R15: R12 screen structure (wave = 16-row tile, all k; 8-group 32KB dbuf
// tiles) + R14 fusion + CHEAP u32 screen keys: k packed into low-10 mantissa
// bits (bias 160 keeps values ~[90,400]; perturbation <=~0.05 absorbed by
// exact re-verify). Top-3 per row via 5-op min/max insert (vs ~28cyc u64).
// Verify: 3 waves re-evaluate candidates in exact fp32 (g_ep), u64-min ->
// np.argmin semantics (ties -> smallest k). z_q + loss fused.

#define IDX_OFF 2097152
#define LOSS_OFF 2129920
#define BIGF 160.0f
#define RL 72
#define U32INF 0xFFFFFFFFu

typedef __attribute__((ext_vector_type(8))) short bf16x8;
typedef __attribute__((ext_vector_type(4))) float f32x4;

__device__ __align__(256) float g_ep[1024 * RL];     // [-2e | ||e||^2+160 | pad]
__device__ __align__(256) float g_enb[1024];         // dense ||e||^2+160
__device__ __align__(256) unsigned short g_bf[64 * 4 * 64 * 8]; // [g][f][lane][j]
__device__ float g_partial[512];

typedef const __attribute__((address_space(1))) void* gvp;
typedef __attribute__((address_space(3))) void* lvp;

__device__ __forceinline__ void gll16(const void* g, void* l) {
    __builtin_amdgcn_global_load_lds((gvp)g, (lvp)l, 16, 0, 0);
}

__device__ __forceinline__ unsigned int f2bf(float f) {   // fp32 -> bf16, RTN-even
    unsigned int u = __float_as_uint(f);
    return (u + 0x7FFFu + ((u >> 16) & 1u)) >> 16;
}

__device__ __forceinline__ unsigned int min16u(unsigned int x) {
#pragma unroll
    for (int o = 1; o < 16; o <<= 1) {
        unsigned int y = __shfl_xor((int)x, o, 64);
        x = y < x ? y : x;
    }
    return x;
}

// ---------------- kernel 0: build e', enb, packed B-frags ------------------
// B-frag layout (R11-verified): group g, lane l (col=l&15, g4=l>>4):
// f=0: bf16(-2e)[g*16+col][g4*8+j]  f=1: ...[32+g4*8+j]  f=2/3: lo-residual.
// g_bf[((g*4+f)*64+l)*8+j] -> linear DMA staging + conflict-free ds_read_b128.
__global__ __launch_bounds__(256) void vq_prep(const float* __restrict__ e) {
    int lane = threadIdx.x & 63;
    int k    = blockIdx.x * 4 + (threadIdx.x >> 6);
    float v  = e[k * 64 + lane];
    float m2 = -2.0f * v;
    float s  = v * v;
#pragma unroll
    for (int o = 32; o; o >>= 1) s += __shfl_xor(s, o, 64);
    g_ep[(size_t)k * RL + lane] = m2;
    if (lane == 0) { g_ep[(size_t)k * RL + 64] = s + BIGF; g_enb[k] = s + BIGF; }
    unsigned hb = f2bf(m2);
    float    hf = __uint_as_float(hb << 16);
    unsigned lb = f2bf(m2 - hf);
    int g  = k >> 4, c = k & 15;
    int ch = lane >> 5, dc = lane & 31;
    int g4 = dc >> 3,  j = dc & 7;
    int l  = g4 * 16 + c;
    g_bf[(size_t)((g * 4 + ch) * 64 + l) * 8 + j]     = (unsigned short)hb;
    g_bf[(size_t)((g * 4 + 2 + ch) * 64 + l) * 8 + j] = (unsigned short)lb;
}

// ---------------- kernel 1: fused screen + verify + epilogue ---------------
// grid 512: 64 rows/block, 4 waves; wave w = rows w*16..w*16+15, ALL 1024
// codes (8 tiles x 8 groups, dbuf). Lane: col=lane&15, row=g4*4+r (C-layout).
__global__ __launch_bounds__(256, 2) void vq_main(const float* __restrict__ z,
                                                  const float* __restrict__ e,
                                                  float* __restrict__ out) {
    __shared__ unsigned short bf[2][8 * 2048];   // 2 x 32 KB
    __shared__ float enb[1024];                  // 4 KB
    __shared__ int   stop[64][3];                // top-3 candidate k per row
    __shared__ unsigned long long skey[3][64];   // exact keys per slot
    __shared__ int   ishare[64];
    __shared__ float lred[4];

    const int t    = threadIdx.x;
    const int lane = t & 63;
    const int w    = __builtin_amdgcn_readfirstlane(t >> 6);  // 0..3
    const int col  = lane & 15;
    const int g4   = lane >> 4;
    const int bid  = blockIdx.x;      // 0..511
    const int b    = bid >> 4;
    const int hw0  = (bid & 15) << 6;

    // stage enb (4 KB) + B-tile 0 (32 KB) via linear DMA
    gll16((const char*)g_enb + w * 1024 + lane * 16, (char*)enb + w * 1024);
#pragma unroll
    for (int i = 0; i < 8; ++i) {
        int seg = w * 8 + i;
        gll16((const char*)g_bf + seg * 1024 + lane * 16, (char*)&bf[0][0] + seg * 1024);
    }

    // A-fragments for this wave's 16 rows (computed -> VGPR-resident)
    const float* zr = z + (size_t)b * 65536 + hw0 + (w * 16 + col);
    bf16x8 zh[2], zl[2];
#pragma unroll
    for (int c = 0; c < 2; ++c)
#pragma unroll
        for (int j = 0; j < 8; ++j) {
            int d = c * 32 + g4 * 8 + j;
            float f = zr[(size_t)d * 1024];
            unsigned hb = f2bf(f);
            float    hf = __uint_as_float(hb << 16);
            unsigned lb = f2bf(f - hf);
            zh[c][j] = (short)hb;
            zl[c][j] = (short)lb;
        }

    unsigned int t0[4], t1[4], t2[4];
#pragma unroll
    for (int r = 0; r < 4; ++r) { t0[r] = U32INF; t1[r] = U32INF; t2[r] = U32INF; }

    __syncthreads();   // DMA drained -> tile 0 + enb visible

    for (int tt = 0; tt < 8; ++tt) {
        const int cur = tt & 1;
        if (tt < 7) {   // prefetch next 32 KB tile (fire-and-forget DMA)
#pragma unroll
            for (int i = 0; i < 8; ++i) {
                int seg = w * 8 + i;
                gll16((const char*)g_bf + (tt + 1) * 32768 + seg * 1024 + lane * 16,
                      (char*)&bf[cur ^ 1][0] + seg * 1024);
            }
        }

        const unsigned short* bfc = &bf[cur][0];
#pragma unroll
        for (int gg = 0; gg < 8; ++gg) {
            const int kc = (tt * 8 + gg) * 16 + col;
            const bf16x8* p = (const bf16x8*)(bfc + gg * 2048);
            bf16x8 eh0 = p[0 * 64 + lane];        // contiguous ds_read_b128
            bf16x8 eh1 = p[1 * 64 + lane];
            bf16x8 el0 = p[2 * 64 + lane];
            bf16x8 el1 = p[3 * 64 + lane];

            f32x4 acc = {0.f, 0.f, 0.f, 0.f};
            acc = __builtin_amdgcn_mfma_f32_16x16x32_bf16(zh[0], eh0, acc, 0, 0, 0);
            acc = __builtin_amdgcn_mfma_f32_16x16x32_bf16(zh[1], eh1, acc, 0, 0, 0);
            acc = __builtin_amdgcn_mfma_f32_16x16x32_bf16(zh[0], el0, acc, 0, 0, 0);
            acc = __builtin_amdgcn_mfma_f32_16x16x32_bf16(zh[1], el1, acc, 0, 0, 0);
            acc = __builtin_amdgcn_mfma_f32_16x16x32_bf16(zl[0], eh0, acc, 0, 0, 0);
            acc = __builtin_amdgcn_mfma_f32_16x16x32_bf16(zl[1], eh1, acc, 0, 0, 0);

            float enbv = enb[kc];
#pragma unroll
            for (int r = 0; r < 4; ++r) {
                float cand = acc[r] + enbv;       // >0 -> uint order = float order
                unsigned int key = (__float_as_uint(cand) & 0xFFFFFC00u) | (unsigned)kc;
                // top-3 insert: 5 scalar u32 min/max ops
                unsigned int a0 = t0[r] < key ? t0[r] : key;
                unsigned int x  = t0[r] < key ? key : t0[r];
                unsigned int a1 = t1[r] < x ? t1[r] : x;
                unsigned int y  = t1[r] < x ? x : t1[r];
                unsigned int a2 = t2[r] < y ? t2[r] : y;
                t0[r] = a0; t1[r] = a1; t2[r] = a2;
            }
        }
        __syncthreads();   // readers done with bf[cur]; next DMA drained
    }

    // per row: global top-3 over the 16 cols (pop-min x3 within 16-lane group)
#pragma unroll
    for (int r = 0; r < 4; ++r) {
        unsigned int x = t0[r], y = t1[r], zz = t2[r];
        unsigned int m1 = min16u(x);
        if (x == m1) { x = y; y = zz; zz = U32INF; }   // keys unique
        unsigned int m2 = min16u(x);
        if (x == m2) { x = y; }
        unsigned int m3 = min16u(x);
        int row = w * 16 + g4 * 4 + r;
        if (col == 0) {
            stop[row][0] = (int)(m1 & 1023u);
            stop[row][1] = (int)(m2 & 1023u);
            stop[row][2] = (int)(m3 & 1023u);
        }
    }
    __syncthreads();

    // ---- verify: waves 0-2 = slot; lane = row; exact fp32 re-evaluate ----
    if (w < 3) {
        int kc = stop[lane][w];
        const float* zbase = z + (size_t)b * 65536 + hw0 + lane;   // L1/L2-hot
        const float* ep    = g_ep + (size_t)kc * RL;
        float d0 = 0.f, d1 = 0.f, d2 = 0.f, d3 = 0.f;
#pragma unroll
        for (int dq = 0; dq < 16; ++dq) {
            float4 ev = *(const float4*)(ep + dq * 4);
            d0 = fmaf(zbase[(size_t)(dq * 4 + 0) * 1024], ev.x, d0);
            d1 = fmaf(zbase[(size_t)(dq * 4 + 1) * 1024], ev.y, d1);
            d2 = fmaf(zbase[(size_t)(dq * 4 + 2) * 1024], ev.z, d2);
            d3 = fmaf(zbase[(size_t)(dq * 4 + 3) * 1024], ev.w, d3);
        }
        float dist = (d0 + d1) + (d2 + d3) + ep[64];
        skey[w][lane] = ((unsigned long long)__float_as_uint(dist) << 32) | (unsigned)kc;
    }
    __syncthreads();

    if (w == 0) {
        unsigned long long ky = skey[0][lane];
        unsigned long long k1 = skey[1][lane];
        unsigned long long k2 = skey[2][lane];
        ky = k1 < ky ? k1 : ky;
        ky = k2 < ky ? k2 : ky;         // exact min; ties -> smallest k
        int idx = (int)(ky & 0xFFFFFFFFull);
        out[IDX_OFF + bid * 64 + lane] = (float)idx;
        ishare[lane] = idx;
    }
    __syncthreads();

    // ---- epilogue: z_q (coalesced along hw) + loss partial ----
    {
        int idx = ishare[lane];
        const float*  zbase = z + (size_t)b * 65536 + hw0 + lane;
        float*        qbase = out + (size_t)b * 65536 + hw0 + lane;
        const float4* er4   = (const float4*)(e + (size_t)idx * 64) + (w << 2);

        float lsum = 0.f;
#pragma unroll
        for (int p = 0; p < 4; ++p) {
            float4 ev = er4[p];                        // gather, L2-resident
            int d = (w << 4) + (p << 2);
            float ezw[4] = {ev.x, ev.y, ev.z, ev.w};
#pragma unroll
            for (int qq = 0; qq < 4; ++qq) {
                float zv = zbase[(size_t)(d + qq) * 1024];
                float df = ezw[qq] - zv;
                lsum = fmaf(df, df, lsum);
                qbase[(size_t)(d + qq) * 1024] = ezw[qq];
            }
        }
#pragma unroll
        for (int o = 32; o; o >>= 1) lsum += __shfl_xor(lsum, o, 64);
        if (lane == 0) lred[w] = lsum;
    }
    __syncthreads();
    if (t == 0)
        g_partial[bid] = (lred[0] + lred[1]) + (lred[2] + lred[3]);
}

// ---------------- kernel 2: loss scalar ------------------------------------
__global__ __launch_bounds__(64) void vq_finish(float* __restrict__ out) {
    int lane = threadIdx.x;
    float s = 0.f;
#pragma unroll
    for (int i = 0; i < 8; ++i) s += g_partial[lane * 8 + i];
#pragma unroll
    for (int o = 32; o; o >>= 1) s += __shfl_xor(s, o, 64);
    // loss = q_latent + 0.25*e_latent = 1.25 * mean((z_q - z)^2)
    if (lane == 0) out[LOSS_OFF] = s * (1.25f / 2097152.0f);
}

extern "C" void kernel_launch(void* const* d_in, const int* in_sizes, int n_in,
                              void* d_out, int out_size, void* d_ws, size_t ws_size,
                              hipStream_t stream) {
    const float* z = (const float*)d_in[0];
    const float* e = (const float*)d_in[1];
    float* out = (float*)d_out;

    vq_prep<<<256, 256, 0, stream>>>(e);
    vq_main<<<512, 256, 0, stream>>>(z, e, out);
    vq_finish<<<1, 64, 0, stream>>>(out);
}